// Round 1
// baseline (167.104 us; speedup 1.0000x reference)
//
#include <hip/hip_runtime.h>

// GCN layer: out = A_sparse @ (X @ W) + bias
// R13: remove the sort machinery entirely.
//  - pass1 758-bucket multisplit (hist + 3-phase scan + LDS reorder + sweep)
//    -> direct per-row scatter: 50000 cursors padded 64B, staging[row][64].
//      1 global atomic + 1 scattered 8B store per edge; contention ~16/cursor.
//  - sortgather (in0/hist/scan/in1 sort + 4 syncthreads) -> pure gather kernel:
//    no LDS, no barriers; 4 subs x 16 lanes (dwordx4/lane = 8 bf16 dims),
//    2-round shfl reduce (32 ops/row vs 96 in the old 8x8 mapping).

#define N_NODES 50000
#define N_EDGES 800000
#define D 128
#define RSLOT 64               // per-row staging capacity (deg ~Poisson(16); P(>=64) ~ 1e-18)
#define CSTRIDE 16             // cursor padding: 16 ints = 64B
#define GEMM_BLOCKS 782        // ceil(50000/64)
#define SC_CHUNK 2048          // edges per scatter block (256 thr * 8)
#define SC_BLOCKS 391          // ceil(800000/2048)
#define GROWS 32               // rows per gather block (4 waves * 8 rows)
#define GATHER_BLOCKS 1563     // ceil(50000/32)

typedef short bf16x8 __attribute__((ext_vector_type(8)));
typedef float f32x4 __attribute__((ext_vector_type(4)));

__device__ inline unsigned short f2bf(float f) {   // RNE f32 -> bf16 bits
    unsigned u = __float_as_uint(f);
    unsigned r = (u + 0x7FFFu + ((u >> 16) & 1u)) >> 16;
    return (unsigned short)r;
}

// ---- ws layout (bytes) ----
// S16:      [0, 12800000)             50000*128*2 bf16
// staging:  [12800000, 38400000)      50000*64 int2 {col, bits(w)}
// gcursor:  [38400000, 41600000)      50000 cursors, 64B apart
// WT16:     [41600000, +34816)        bf16 W^T padded [128][136]

// ---------------- K0: W^T bf16 prep + cursor zero ----------------
__global__ __launch_bounds__(256) void wprep_kernel(const float* __restrict__ W,
                                                    unsigned short* __restrict__ WT,
                                                    int* __restrict__ gcursor) {
    int idx = blockIdx.x * 256 + threadIdx.x;
    if (idx < 128 * 128) {
        int k = idx >> 7, n = idx & 127;
        WT[n * 136 + k] = f2bf(W[idx]);
    }
    for (int i = idx; i < N_NODES * CSTRIDE; i += 512 * 256) gcursor[i] = 0;
}

// ---------------- K1: fused gemm (blocks < GEMM_BLOCKS) + scatter ----------
__global__ __launch_bounds__(256) void fused_kernel(const float* __restrict__ X,
                                                    const unsigned short* __restrict__ WT,
                                                    unsigned short* __restrict__ S16,
                                                    const int* __restrict__ ei,
                                                    const float* __restrict__ ew,
                                                    int* __restrict__ gcursor,
                                                    int2* __restrict__ staging) {
    __shared__ __align__(16) char shmem[52224];
    const int t = threadIdx.x;
    const int lane = t & 63, wid = t >> 6;

    if (blockIdx.x < GEMM_BLOCKS) {
        // ================= GEMM: S16 = bf16(X @ W) =================
        unsigned short* wt = (unsigned short*)shmem;            // [128][136]
        unsigned short* xt = (unsigned short*)(shmem + 34816);  // [64][136]
        const int row0 = blockIdx.x * 64;

        // stage W^T bf16: pure uint4 memcpy, conflict-free, no converts
        const uint4* WTg = (const uint4*)WT;
        uint4* wl = (uint4*)wt;
#pragma unroll
        for (int i = 0; i < 9; ++i) {
            int idx = t + 256 * i;                // 2176 uint4 total
            if (idx < 2176) wl[idx] = WTg[idx];
        }
        const float4* X4 = (const float4*)X;
#pragma unroll
        for (int i = 0; i < 8; ++i) {
            int idx4 = t + 256 * i;
            int r = idx4 >> 5, c4 = idx4 & 31;
            int gr = row0 + r;
            float4 v = make_float4(0.f, 0.f, 0.f, 0.f);
            if (gr < N_NODES) v = X4[gr * 32 + c4];
            ushort4 u = make_ushort4(f2bf(v.x), f2bf(v.y), f2bf(v.z), f2bf(v.w));
            *(ushort4*)&xt[r * 136 + c4 * 4] = u;
        }
        __syncthreads();

        const int m = lane & 15;
        const int q = lane >> 4;
        const int rbase = wid * 16;

        f32x4 acc[8];
#pragma unroll
        for (int nt = 0; nt < 8; ++nt) acc[nt] = (f32x4){0.f, 0.f, 0.f, 0.f};
#pragma unroll
        for (int ks = 0; ks < 4; ++ks) {
            bf16x8 a = *(const bf16x8*)&xt[(rbase + m) * 136 + ks * 32 + q * 8];
#pragma unroll
            for (int nt = 0; nt < 8; ++nt) {
                bf16x8 b = *(const bf16x8*)&wt[(nt * 16 + m) * 136 + ks * 32 + q * 8];
                acc[nt] = __builtin_amdgcn_mfma_f32_16x16x32_bf16(a, b, acc[nt], 0, 0, 0);
            }
        }
        __syncthreads();
#pragma unroll
        for (int nt = 0; nt < 8; ++nt) {
            int col = nt * 16 + m;
#pragma unroll
            for (int r = 0; r < 4; ++r) {
                int rl = rbase + q * 4 + r;
                xt[rl * 136 + col] = f2bf(acc[nt][r]);
            }
        }
        __syncthreads();
#pragma unroll
        for (int i = 0; i < 4; ++i) {
            int id = t + 256 * i;
            int r = id >> 4, c8 = (id & 15) * 8;
            int gr = row0 + r;
            if (gr < N_NODES)
                *(uint4*)&S16[gr * 128 + c8] = *(const uint4*)&xt[r * 136 + c8];
        }
    } else {
        // ================= direct per-row scatter =================
        const int base = (blockIdx.x - GEMM_BLOCKS) * SC_CHUNK;
#pragma unroll
        for (int i = 0; i < 8; ++i) {
            int e = base + t + 256 * i;
            if (e < N_EDGES) {
                int row = ei[e];
                int col = ei[N_EDGES + e];
                float w = ew[e];
                int slot = atomicAdd(&gcursor[row * CSTRIDE], 1);
                if (slot < RSLOT)
                    staging[row * RSLOT + slot] = make_int2(col, __float_as_int(w));
            }
        }
    }
}

// ---------------- K2: pure gather (no LDS, no barriers) ----------------
// Block = 256 thr = 4 waves; wave wv owns rows [blk*32 + wv*8, +8).
// Lane: sub = lane>>4 (4 edge streams), q = lane&15 owns dims q*8..q*8+7
// (one dwordx4 of S16). 2-round shfl_xor reduce; sub 0 stores 512B/row.
__global__ __launch_bounds__(256) void gather_kernel(const unsigned short* __restrict__ S16,
                                                     const int* __restrict__ gcursor,
                                                     const int2* __restrict__ staging,
                                                     const float* __restrict__ bias,
                                                     float* __restrict__ out) {
    const int t = threadIdx.x;
    const int wv = t >> 6;
    const int lane = t & 63;
    const int sub = lane >> 4;
    const int q = lane & 15;
    const uint4* S4 = (const uint4*)S16;     // row stride: 16 uint4
    const float4* bias4 = (const float4*)bias;
    const float4 b0 = bias4[q * 2];
    const float4 b1 = bias4[q * 2 + 1];
    const int rbase = blockIdx.x * GROWS + wv * 8;

    for (int r8 = 0; r8 < 8; ++r8) {
        const int row = rbase + r8;
        if (row >= N_NODES) break;
        int cnt = gcursor[row * CSTRIDE];
        if (cnt > RSLOT) cnt = RSLOT;

        float acc[8];
#pragma unroll
        for (int i = 0; i < 8; ++i) acc[i] = 0.f;

        for (int p = sub; p < cnt; p += 4) {
            int2 e = staging[row * RSLOT + p];   // 4 addrs/wave, 32B span
            float w = __int_as_float(e.y);
            int col = e.x;
            uint4 v = S4[col * 16 + q];          // 16 lanes x 16B = full 256B row
            acc[0] += __uint_as_float(v.x << 16) * w;
            acc[1] += __uint_as_float(v.x & 0xFFFF0000u) * w;
            acc[2] += __uint_as_float(v.y << 16) * w;
            acc[3] += __uint_as_float(v.y & 0xFFFF0000u) * w;
            acc[4] += __uint_as_float(v.z << 16) * w;
            acc[5] += __uint_as_float(v.z & 0xFFFF0000u) * w;
            acc[6] += __uint_as_float(v.w << 16) * w;
            acc[7] += __uint_as_float(v.w & 0xFFFF0000u) * w;
        }
#pragma unroll
        for (int i = 0; i < 8; ++i) acc[i] += __shfl_xor(acc[i], 16, 64);
#pragma unroll
        for (int i = 0; i < 8; ++i) acc[i] += __shfl_xor(acc[i], 32, 64);

        if (sub == 0) {
            float4 o0 = make_float4(acc[0] + b0.x, acc[1] + b0.y,
                                    acc[2] + b0.z, acc[3] + b0.w);
            float4 o1 = make_float4(acc[4] + b1.x, acc[5] + b1.y,
                                    acc[6] + b1.z, acc[7] + b1.w);
            ((float4*)out)[row * 32 + q * 2] = o0;       // 16 lanes x 2 x 16B = 512B row
            ((float4*)out)[row * 32 + q * 2 + 1] = o1;
        }
    }
}

extern "C" void kernel_launch(void* const* d_in, const int* in_sizes, int n_in,
                              void* d_out, int out_size, void* d_ws, size_t ws_size,
                              hipStream_t stream) {
    const float* X    = (const float*)d_in[0];
    const int*   ei   = (const int*)d_in[1];
    const float* ew   = (const float*)d_in[2];
    const float* W    = (const float*)d_in[3];
    const float* bias = (const float*)d_in[4];
    float* out = (float*)d_out;

    char* ws = (char*)d_ws;
    unsigned short* S16 = (unsigned short*)(ws);
    int2* staging = (int2*)(ws + 12800000);
    int*  gcursor = (int*)(ws + 38400000);
    unsigned short* WT16 = (unsigned short*)(ws + 41600000);

    wprep_kernel<<<512, 256, 0, stream>>>(W, WT16, gcursor);
    fused_kernel<<<GEMM_BLOCKS + SC_BLOCKS, 256, 0, stream>>>(X, WT16, S16, ei, ew,
                                                              gcursor, staging);
    gather_kernel<<<GATHER_BLOCKS, 256, 0, stream>>>(S16, gcursor, staging, bias, out);
}

// Round 3
// 133.248 us; speedup vs baseline: 1.2541x; 1.2541x over previous
//
#include <hip/hip_runtime.h>

// GCN layer: out = A_sparse @ (X @ W) + bias
// R15 = R14 with compile fix (FMA8 macro param `w` collided with uint4 member
// `.w` -> expanded to `.w0`; now an inline function).
//  - LPT ordering: pass1 blocks dispatched FIRST (blockIdx < PASS1_BLOCKS).
//  - sortgather phase B: 4 subs x 16 lanes (1 dwordx4/lane = full 256B row),
//    8 accs, 2-round shfl reduce, 2-deep edge pipeline.

#define N_NODES 50000
#define N_EDGES 800000
#define D 128
#define BROWS 66               // rows per bucket
#define NBUCKET 758            // ceil(50000/66)
#define SLOT 1536              // per-bucket capacity (mean 1052, +15 sigma)
#define CHUNK 4096             // edges per pass1 block
#define EPT 16                 // CHUNK/256
#define GEMM_BLOCKS 782        // ceil(50000/64)
#define PASS1_BLOCKS 196       // ceil(800000/4096)
#define CSTRIDE 16             // gcursor padding: 16 ints = 64B per cursor

typedef short bf16x8 __attribute__((ext_vector_type(8)));
typedef float f32x4 __attribute__((ext_vector_type(4)));

__device__ inline unsigned short f2bf(float f) {   // RNE f32 -> bf16 bits
    unsigned u = __float_as_uint(f);
    unsigned r = (u + 0x7FFFu + ((u >> 16) & 1u)) >> 16;
    return (unsigned short)r;
}

__device__ inline void fma8(float* acc, uint4 v, float w) {
    acc[0] += __uint_as_float(v.x << 16) * w;
    acc[1] += __uint_as_float(v.x & 0xFFFF0000u) * w;
    acc[2] += __uint_as_float(v.y << 16) * w;
    acc[3] += __uint_as_float(v.y & 0xFFFF0000u) * w;
    acc[4] += __uint_as_float(v.z << 16) * w;
    acc[5] += __uint_as_float(v.z & 0xFFFF0000u) * w;
    acc[6] += __uint_as_float(v.w << 16) * w;
    acc[7] += __uint_as_float(v.w & 0xFFFF0000u) * w;
}

// ---- ws layout (bytes) ----
// S16:      [0, 12800000)            50000*128*2 bf16
// staging:  [12800000, +9314304)     758*1536 int2 (lrow<<16|col, bits(w))
// gcursor:  [22114304, +48512)       758 cursors, 64B apart
// WT16:     [22162816, +34816)       bf16 W^T padded [128][136]

// ---------------- K0: W^T bf16 prep + cursor zero (once) ----------------
__global__ __launch_bounds__(256) void wprep_kernel(const float* __restrict__ W,
                                                    unsigned short* __restrict__ WT,
                                                    int* __restrict__ gcursor) {
    int idx = blockIdx.x * 256 + threadIdx.x;
    if (idx < 128 * 128) {
        int k = idx >> 7, n = idx & 127;
        WT[n * 136 + k] = f2bf(W[idx]);
    }
    if (idx < NBUCKET * CSTRIDE) gcursor[idx] = 0;
}

// ---------------- K1: fused pass1 (blocks < PASS1_BLOCKS) + gemm ----------
__global__ __launch_bounds__(256) void fused_kernel(const float* __restrict__ X,
                                                    const unsigned short* __restrict__ WT,
                                                    unsigned short* __restrict__ S16,
                                                    const int* __restrict__ ei,
                                                    const float* __restrict__ ew,
                                                    int* __restrict__ gcursor,
                                                    int2* __restrict__ staging) {
    __shared__ __align__(16) char shmem[52224];
    const int t = threadIdx.x;
    const int lane = t & 63, wid = t >> 6;

    if (blockIdx.x >= PASS1_BLOCKS) {
        // ================= GEMM: S16 = bf16(X @ W) =================
        unsigned short* wt = (unsigned short*)shmem;            // [128][136]
        unsigned short* xt = (unsigned short*)(shmem + 34816);  // [64][136]
        const int row0 = (blockIdx.x - PASS1_BLOCKS) * 64;

        // stage W^T bf16: pure uint4 memcpy, conflict-free, no converts
        const uint4* WTg = (const uint4*)WT;
        uint4* wl = (uint4*)wt;
#pragma unroll
        for (int i = 0; i < 9; ++i) {
            int idx = t + 256 * i;                // 2176 uint4 total
            if (idx < 2176) wl[idx] = WTg[idx];
        }
        const float4* X4 = (const float4*)X;
#pragma unroll
        for (int i = 0; i < 8; ++i) {
            int idx4 = t + 256 * i;
            int r = idx4 >> 5, c4 = idx4 & 31;
            int gr = row0 + r;
            float4 v = make_float4(0.f, 0.f, 0.f, 0.f);
            if (gr < N_NODES) v = X4[gr * 32 + c4];
            ushort4 u = make_ushort4(f2bf(v.x), f2bf(v.y), f2bf(v.z), f2bf(v.w));
            *(ushort4*)&xt[r * 136 + c4 * 4] = u;
        }
        __syncthreads();

        const int m = lane & 15;
        const int q = lane >> 4;
        const int rbase = wid * 16;

        f32x4 acc[8];
#pragma unroll
        for (int nt = 0; nt < 8; ++nt) acc[nt] = (f32x4){0.f, 0.f, 0.f, 0.f};
#pragma unroll
        for (int ks = 0; ks < 4; ++ks) {
            bf16x8 a = *(const bf16x8*)&xt[(rbase + m) * 136 + ks * 32 + q * 8];
#pragma unroll
            for (int nt = 0; nt < 8; ++nt) {
                bf16x8 b = *(const bf16x8*)&wt[(nt * 16 + m) * 136 + ks * 32 + q * 8];
                acc[nt] = __builtin_amdgcn_mfma_f32_16x16x32_bf16(a, b, acc[nt], 0, 0, 0);
            }
        }
        __syncthreads();
#pragma unroll
        for (int nt = 0; nt < 8; ++nt) {
            int col = nt * 16 + m;
#pragma unroll
            for (int r = 0; r < 4; ++r) {
                int rl = rbase + q * 4 + r;
                xt[rl * 136 + col] = f2bf(acc[nt][r]);
            }
        }
        __syncthreads();
#pragma unroll
        for (int i = 0; i < 4; ++i) {
            int id = t + 256 * i;
            int r = id >> 4, c8 = (id & 15) * 8;
            int gr = row0 + r;
            if (gr < N_NODES)
                *(uint4*)&S16[gr * 128 + c8] = *(const uint4*)&xt[r * 136 + c8];
        }
    } else {
        // ================= PASS1: bucket multisplit (758 buckets) =========
        int* bufx            = (int*)shmem;                         // [4096] 16KB
        int* bufw            = (int*)(shmem + 16384);               // [4096] 16KB
        unsigned short* bof  = (unsigned short*)(shmem + 32768);    // [4096] 8KB
        int* hist            = (int*)(shmem + 40960);               // [768]
        int* lcur            = (int*)(shmem + 44032);               // [768]
        int* bmg             = (int*)(shmem + 47104);               // [768]
        int* wsum            = (int*)(shmem + 50176);               // [4]
        const int base = blockIdx.x * CHUNK;

        hist[t] = 0;
        hist[t + 256] = 0;
        hist[t + 512] = 0;
        __syncthreads();

        int rows[EPT];
        int bkt[EPT];
#pragma unroll
        for (int i = 0; i < EPT; ++i) {
            int e = base + t + 256 * i;
            rows[i] = (e < N_EDGES) ? ei[e] : -1;
            bkt[i] = (rows[i] >= 0) ? (rows[i] / BROWS) : -1;
            if (bkt[i] >= 0) atomicAdd(&hist[bkt[i]], 1);
        }
        __syncthreads();

        // three-phase wave-shfl exclusive scan of hist[768]
        int run = 0, exv[3], vv[3];
#pragma unroll
        for (int ph = 0; ph < 3; ++ph) {
            int v = hist[ph * 256 + t];
            vv[ph] = v;
            int incl = v;
#pragma unroll
            for (int off = 1; off < 64; off <<= 1) {
                int x = __shfl_up(incl, off, 64);
                if (lane >= off) incl += x;
            }
            if (lane == 63) wsum[wid] = incl;
            __syncthreads();
            int pre = 0, tot = 0;
#pragma unroll
            for (int w = 0; w < 4; ++w) {
                int x = wsum[w];
                if (w < wid) pre += x;
                tot += x;
            }
            exv[ph] = run + incl - v + pre;
            run += tot;
            __syncthreads();
        }
        const int total = run;
        lcur[t] = exv[0];
        lcur[t + 256] = exv[1];
        lcur[t + 512] = exv[2];
#pragma unroll
        for (int ph = 0; ph < 3; ++ph) {
            int b = ph * 256 + t;
            if (b < NBUCKET) {
                int v = vv[ph];
                if (v > 0) {
                    int gb = atomicAdd(&gcursor[b * CSTRIDE], v);
                    bmg[b] = b * SLOT + gb - exv[ph];
                }
            }
        }
        __syncthreads();

        // local reorder into bucket-contiguous LDS (SoA: 4B writes, 2-way max)
#pragma unroll
        for (int i = 0; i < EPT; ++i) {
            if (rows[i] >= 0) {
                int e = base + t + 256 * i;
                int col = ei[N_EDGES + e];
                float w = ew[e];
                int b = bkt[i];
                int lp = atomicAdd(&lcur[b], 1);
                int lrow = rows[i] - b * BROWS;     // 0..65
                bufx[lp] = (int)(((unsigned)lrow << 16) | (unsigned)col);
                bufw[lp] = __float_as_int(w);
                bof[lp] = (unsigned short)b;
            }
        }
        __syncthreads();

        // coalesced sweep: consecutive lp in same bucket -> consecutive gaddr
        for (int lp = t; lp < total; lp += 256) {
            int b = bof[lp];
            int g = bmg[b] + lp;
            if (g < (b + 1) * SLOT)
                staging[g] = make_int2(bufx[lp], bufw[lp]);   // overflow guard
        }
    }
}

// ---------------- K2: fused per-bucket sort + gather ----------------
// One 512-thread block per 66-row bucket. Phase A: bucket -> in0, int-atomic
// hist by local row, wave scan, sort directly into in1 (no perm indirection).
// Phase B: wave wv does rows wv, wv+8, ...; 4 subs of 16 lanes = each sub
// reads a full 256B S16 row with one dwordx4/lane; 2-deep edge pipeline;
// 2-round shfl_xor reduce; sub 0 stores 512B/row (+bias).
__global__ __launch_bounds__(512) void sortgather_kernel(const unsigned short* __restrict__ S16,
                                                         const int* __restrict__ gcursor,
                                                         const int2* __restrict__ staging,
                                                         const float* __restrict__ bias,
                                                         float* __restrict__ out) {
    __shared__ int2 in0[SLOT];              // 12288 B
    __shared__ int2 in1[SLOT];              // 12288 B
    __shared__ int hist[128];               // entries >= BROWS stay 0
    __shared__ int exs[128];
    __shared__ int lcur[128];
    __shared__ int wsum[2];
    const int t = threadIdx.x;
    const int b = blockIdx.x;
    const int lane = t & 63;
    int cnt = gcursor[b * CSTRIDE];
    if (cnt > SLOT) cnt = SLOT;

    if (t < 128) hist[t] = 0;
    __syncthreads();

    for (int i = t; i < cnt; i += 512) {
        int2 v = staging[b * SLOT + i];
        in0[i] = v;
        atomicAdd(&hist[((unsigned)v.x >> 16) & 127u], 1);
    }
    __syncthreads();

    // scan hist[128] using threads 0..127
    int v = 0, incl = 0;
    if (t < 128) {
        v = hist[t];
        incl = v;
#pragma unroll
        for (int off = 1; off < 64; off <<= 1) {
            int x = __shfl_up(incl, off, 64);
            if (lane >= off) incl += x;
        }
        if (lane == 63) wsum[t >> 6] = incl;
    }
    __syncthreads();
    if (t < 128) {
        int pre = (t >= 64) ? wsum[0] : 0;
        int ex = incl - v + pre;
        exs[t] = ex;
        lcur[t] = ex;
    }
    __syncthreads();

    // sort payload directly into in1 (row-contiguous)
    for (int i = t; i < cnt; i += 512) {
        int2 e = in0[i];
        int lr = (int)(((unsigned)e.x >> 16) & 127u);
        int p = atomicAdd(&lcur[lr], 1);
        in1[p] = e;
    }
    __syncthreads();

    // gather
    const int wv = t >> 6;                   // 0..7
    const int sub = lane >> 4;               // 0..3 edge sub-streams
    const int q = lane & 15;                 // owns dims q*8..q*8+7
    const uint4* S4 = (const uint4*)S16;     // row stride: 16 uint4
    const float4* bias4 = (const float4*)bias;
    const float4 b0 = bias4[q * 2];
    const float4 b1 = bias4[q * 2 + 1];

    for (int rr = wv; rr < BROWS; rr += 8) {
        const int beg = exs[rr];
        const int end = beg + hist[rr];
        float acc[8];
#pragma unroll
        for (int i = 0; i < 8; ++i) acc[i] = 0.f;

        int p = beg + sub;
        // 2-deep pipeline: two edges' loads in flight before their FMAs
        for (; p + 4 < end; p += 8) {
            int2 cw0 = in1[p];
            int2 cw1 = in1[p + 4];
            uint4 v0 = S4[(cw0.x & 0xFFFF) * 16 + q];
            uint4 v1 = S4[(cw1.x & 0xFFFF) * 16 + q];
            float w0 = __int_as_float(cw0.y);
            float w1 = __int_as_float(cw1.y);
            fma8(acc, v0, w0);
            fma8(acc, v1, w1);
        }
        if (p < end) {
            int2 cw = in1[p];
            uint4 v2 = S4[(cw.x & 0xFFFF) * 16 + q];
            float w = __int_as_float(cw.y);
            fma8(acc, v2, w);
        }
#pragma unroll
        for (int i = 0; i < 8; ++i) acc[i] += __shfl_xor(acc[i], 16, 64);
#pragma unroll
        for (int i = 0; i < 8; ++i) acc[i] += __shfl_xor(acc[i], 32, 64);

        int gr = b * BROWS + rr;
        if (sub == 0 && gr < N_NODES) {
            float4 o0 = make_float4(acc[0] + b0.x, acc[1] + b0.y,
                                    acc[2] + b0.z, acc[3] + b0.w);
            float4 o1 = make_float4(acc[4] + b1.x, acc[5] + b1.y,
                                    acc[6] + b1.z, acc[7] + b1.w);
            ((float4*)out)[gr * 32 + q * 2] = o0;
            ((float4*)out)[gr * 32 + q * 2 + 1] = o1;
        }
    }
}

extern "C" void kernel_launch(void* const* d_in, const int* in_sizes, int n_in,
                              void* d_out, int out_size, void* d_ws, size_t ws_size,
                              hipStream_t stream) {
    const float* X    = (const float*)d_in[0];
    const int*   ei   = (const int*)d_in[1];
    const float* ew   = (const float*)d_in[2];
    const float* W    = (const float*)d_in[3];
    const float* bias = (const float*)d_in[4];
    float* out = (float*)d_out;

    char* ws = (char*)d_ws;
    unsigned short* S16 = (unsigned short*)(ws);
    int2* staging = (int2*)(ws + 12800000);
    int*  gcursor = (int*)(ws + 22114304);
    unsigned short* WT16 = (unsigned short*)(ws + 22162816);

    wprep_kernel<<<64, 256, 0, stream>>>(W, WT16, gcursor);
    fused_kernel<<<GEMM_BLOCKS + PASS1_BLOCKS, 256, 0, stream>>>(X, WT16, S16, ei, ew,
                                                                 gcursor, staging);
    sortgather_kernel<<<NBUCKET, 512, 0, stream>>>(S16, gcursor, staging, bias, out);
}